// Round 1
// 1610.232 us; speedup vs baseline: 1.0230x; 1.0230x over previous
//
#include <hip/hip_runtime.h>
#include <hip/hip_bf16.h>

// ---------------- problem constants ----------------
#define DMODEL 512
#define NH     8
#define DHEAD  64
#define DFF    2048
#define NLAYER 6
#define BB     8
#define TT     1024
#define NTOK   (BB*TT)                 // 8192 rows
#define ACTE   ((size_t)NTOK*DMODEL)   // 4,194,304 elements

// Q pre-scale: (1/sqrt(64)) * log2(e)  -> scores arrive in exp2 domain
#define QSCALE 0.18033688011112042f

// defer-max threshold (exp2 domain): skip O-rescale while smax-m <= 8 (P <= 256)
#define RESCALE_THR 8.0f

// Pl row stride in shorts: 80 (160B) -> b128 read bank-starts 8(l15&3)+4q (4-way, was 8-way at 72)
#define PST 80

typedef __bf16  bf16x8  __attribute__((ext_vector_type(8)));
typedef float   float4v __attribute__((ext_vector_type(4)));
typedef short   short4v __attribute__((ext_vector_type(4)));
typedef short   short8v __attribute__((ext_vector_type(8)));

__device__ __forceinline__ unsigned short f2bf(float f) {
    __hip_bfloat16 h = __float2bfloat16(f);
    return *reinterpret_cast<unsigned short*>(&h);
}

// async global->LDS, 16B/lane. LDS base wave-uniform; HW adds lane*16.
// Global address is PER-LANE -> used to write a swizzled LDS layout for free.
__device__ __forceinline__ void gl_lds16(const void* g, void* l) {
    __builtin_amdgcn_global_load_lds((const __attribute__((address_space(1))) void*)g,
                                     (__attribute__((address_space(3))) void*)l, 16, 0, 0);
}

// ---------------- merged small-weight transpose (8 types x 6 layers) ----------------
struct Tr8Args {
    const float* src[8];
    unsigned short* dst[8];
    int dstL[8];    // per-layer dst stride (elements)
    int rowOff[8];
};
__global__ __launch_bounds__(256) void transpose8_kernel(Tr8Args a)
{
    __shared__ float tile[64][65];
    const int type = blockIdx.z / 6, lyr = blockIdx.z % 6;
    const float* src = a.src[type] + (size_t)lyr * 512 * 512;
    unsigned short* dst = a.dst[type] + (size_t)lyr * a.dstL[type];
    const int rowOff = a.rowOff[type];
    const int k0 = blockIdx.x * 64, n0 = blockIdx.y * 64;
    const int tid = threadIdx.x;
#pragma unroll
    for (int rep = 0; rep < 16; ++rep) {
        int idx = rep * 256 + tid;
        int r = idx >> 6, c = idx & 63;
        tile[r][c] = src[(size_t)(k0 + r) * 512 + n0 + c];
    }
    __syncthreads();
#pragma unroll
    for (int rep = 0; rep < 16; ++rep) {
        int idx = rep * 256 + tid;
        int r = idx >> 6, c = idx & 63;
        dst[(size_t)(rowOff + n0 + r) * 512 + k0 + c] = f2bf(tile[c][r]);
    }
}

// ---------------- generic transpose (W1/W2) ----------------
__global__ __launch_bounds__(256) void transpose_conv_kernel(
    const float* __restrict__ W, unsigned short* __restrict__ Wt, int K, int N,
    size_t dstL, int rowOff)
{
    __shared__ float tile[64][65];
    const float* src = W + (size_t)blockIdx.z * K * N;
    unsigned short* dst = Wt + (size_t)blockIdx.z * dstL;
    const int k0 = blockIdx.x * 64, n0 = blockIdx.y * 64;
    const int tid = threadIdx.x;
#pragma unroll
    for (int rep = 0; rep < 16; ++rep) {
        int idx = rep * 256 + tid;
        int r = idx >> 6, c = idx & 63;
        tile[r][c] = src[(size_t)(k0 + r) * N + n0 + c];
    }
    __syncthreads();
#pragma unroll
    for (int rep = 0; rep < 16; ++rep) {
        int idx = rep * 256 + tid;
        int r = idx >> 6, c = idx & 63;
        dst[(size_t)(rowOff + n0 + r) * K + k0 + c] = f2bf(tile[c][r]);
    }
}

// ---------------- fp32 -> bf16 convert ----------------
__global__ __launch_bounds__(256) void conv_bf16_kernel(
    const float* __restrict__ in, unsigned short* __restrict__ o)
{
    int i = (blockIdx.x * 256 + threadIdx.x) * 4;
    float4v v = *(const float4v*)(in + i);
    short4v w;
    w[0] = (short)f2bf(v[0]); w[1] = (short)f2bf(v[1]);
    w[2] = (short)f2bf(v[2]); w[3] = (short)f2bf(v[3]);
    *(short4v*)(o + i) = w;
}

// ---------------- embedding + sinusoidal PE (bf16 out only) ----------------
__global__ __launch_bounds__(256) void embed_kernel(
    const int* __restrict__ dec, const float* __restrict__ emb,
    unsigned short* __restrict__ xb)
{
    const int row = blockIdx.x;            // 0..8191
    const int t = row & (TT - 1);
    const int tid = threadIdx.x;
    const int tok = dec[row];
#pragma unroll
    for (int rep = 0; rep < 2; ++rep) {
        int c = tid + rep * 256;
        float e = (tok != 0) ? emb[(size_t)tok * DMODEL + c] : 0.f;
        int j = c >> 1;
        float freq = __expf(-(float)(2 * j) * (9.210340371976184f / 512.f));
        float ang = (float)t * freq;
        float pe = (c & 1) ? cosf(ang) : sinf(ang);
        xb[(size_t)row * DMODEL + c] = f2bf(e + pe);
    }
}

// ---------------- residual add + LayerNorm, wave-per-row ----------------
// y = LN(t[0..ACTE) + t[ACTE..2*ACTE) + bf16(xb));  writes xb (bf16) or xout (fp32).
__global__ __launch_bounds__(256) void add_ln2(
    const float* __restrict__ t, unsigned short* __restrict__ xb,
    float* __restrict__ xout)
{
    const int lane = threadIdx.x & 63;
    const int row = blockIdx.x * 4 + (threadIdx.x >> 6);
    const size_t idx = (size_t)row * DMODEL + lane * 8;
    float4v t0 = *(const float4v*)(t + idx);
    float4v t1 = *(const float4v*)(t + idx + 4);
    float4v u0 = *(const float4v*)(t + ACTE + idx);
    float4v u1 = *(const float4v*)(t + ACTE + idx + 4);
    bf16x8 rb = *(const bf16x8*)(xb + idx);
    float v[8];
#pragma unroll
    for (int k = 0; k < 4; ++k) {
        v[k] = t0[k] + u0[k] + (float)rb[k];
        v[4 + k] = t1[k] + u1[k] + (float)rb[4 + k];
    }
    float s = 0.f, sq = 0.f;
#pragma unroll
    for (int k = 0; k < 8; ++k) { s += v[k]; sq += v[k] * v[k]; }
#pragma unroll
    for (int o = 1; o < 64; o <<= 1) { s += __shfl_xor(s, o); sq += __shfl_xor(sq, o); }
    float mu = s * (1.f / 512.f);
    float var = sq * (1.f / 512.f) - mu * mu;
    float rstd = rsqrtf(var + 1e-5f);
    if (xout) {
        float4v y0, y1;
#pragma unroll
        for (int k = 0; k < 4; ++k) { y0[k] = (v[k] - mu) * rstd; y1[k] = (v[4 + k] - mu) * rstd; }
        *(float4v*)(xout + idx) = y0;
        *(float4v*)(xout + idx + 4) = y1;
    } else {
        short8v w;
#pragma unroll
        for (int k = 0; k < 8; ++k) w[k] = (short)f2bf((v[k] - mu) * rstd);
        *(short8v*)(xb + idx) = w;
    }
}

// ---------------- bf16 GEMM: C[M,N] = A[M,K] * Bt[N,K]^T ----------------
// 128x128 tile, BK=32, 2x2 waves, 4x4 MFMA 16x16x32 per wave.
// LDS XOR-swizzled 16B chunks -> conflict-free ds_read_b128 fragment reads.
// EPI: 0 fp32 (+SPLITK partials); 1 relu->bf16; 2 head-scatter, Q (which==0)
// pre-scaled by QSCALE (exp2-domain softmax); 3 all-layer KV scatter.
template <int EPI, int SPLITK = 1>
__global__ __launch_bounds__(256) void gemm_bt(
    const unsigned short* __restrict__ A,
    const unsigned short* __restrict__ Bt,
    float* __restrict__ Cf,
    unsigned short* __restrict__ Cb,
    int M, int N, int K)
{
    __shared__ __attribute__((aligned(16))) short As[128 * 32];
    __shared__ __attribute__((aligned(16))) short Bs[128 * 32];
    const int tid = threadIdx.x;
    const int lane = tid & 63, wv = tid >> 6;
    const int quad = lane >> 4, l15 = lane & 15;
    const int m0 = blockIdx.x * 128, n0 = blockIdx.y * 128;
    const int wm = wv & 1, wn = wv >> 1;

    float4v acc[4][4];
#pragma unroll
    for (int i = 0; i < 4; ++i)
#pragma unroll
        for (int j = 0; j < 4; ++j) acc[i][j] = (float4v){0.f, 0.f, 0.f, 0.f};

    const int Kc = K / SPLITK;
    const int kbeg = (SPLITK > 1) ? (int)blockIdx.z * Kc : 0;
    for (int k0 = kbeg; k0 < kbeg + Kc; k0 += 32) {
#pragma unroll
        for (int i = 0; i < 2; ++i) {
            const int inst = wv * 2 + i;                  // 0..7, 1KB each
            const int row = inst * 16 + (lane >> 2);      // tile row this lane fills
            const int cb = (lane & 3) ^ ((row >> 1) & 3); // swizzled 16B chunk
            gl_lds16(A + (size_t)(m0 + row) * K + k0 + cb * 8, (char*)As + inst * 1024);
            gl_lds16(Bt + (size_t)(n0 + row) * K + k0 + cb * 8, (char*)Bs + inst * 1024);
        }
        __syncthreads();
        bf16x8 a[4], b[4];
#pragma unroll
        for (int i = 0; i < 4; ++i) {
            const int r = wm * 64 + i * 16 + l15;
            const int st = quad ^ ((r >> 1) & 3);
            a[i] = *(const bf16x8*)&As[r * 32 + st * 8];
        }
#pragma unroll
        for (int j = 0; j < 4; ++j) {
            const int r = wn * 64 + j * 16 + l15;
            const int st = quad ^ ((r >> 1) & 3);
            b[j] = *(const bf16x8*)&Bs[r * 32 + st * 8];
        }
#pragma unroll
        for (int i = 0; i < 4; ++i)
#pragma unroll
            for (int j = 0; j < 4; ++j)
                acc[i][j] = __builtin_amdgcn_mfma_f32_16x16x32_bf16(a[i], b[j], acc[i][j], 0, 0, 0);
        __syncthreads();
    }

    const size_t zoff = (SPLITK > 1) ? (size_t)blockIdx.z * ACTE : 0;
#pragma unroll
    for (int i = 0; i < 4; ++i) {
        const int row_base = m0 + wm * 64 + i * 16 + quad * 4;
#pragma unroll
        for (int j = 0; j < 4; ++j) {
            const int col = n0 + wn * 64 + j * 16 + l15;
#pragma unroll
            for (int r = 0; r < 4; ++r) {
                const int row = row_base + r;
                const float v = acc[i][j][r];
                if (EPI == 0) {
                    Cf[zoff + (size_t)row * N + col] = v;
                } else if (EPI == 1) {
                    Cb[(size_t)row * N + col] = f2bf(fmaxf(v, 0.f));
                } else if (EPI == 2) {
                    const int which = col >> 9;
                    const float sc = (which == 0) ? QSCALE : 1.f;  // pre-scale Q
                    const int b_ = row >> 10, t = row & (TT - 1);
                    const int h = (col >> 6) & 7, d = col & 63;
                    Cb[(size_t)which * ACTE + (((size_t)(b_ * NH + h)) * TT + t) * DHEAD + d] = f2bf(v * sc);
                } else {
                    const int layer = col >> 10, which = (col >> 9) & 1;
                    const int b_ = row >> 10, t = row & (TT - 1);
                    const int h = (col >> 6) & 7, d = col & 63;
                    Cb[(size_t)(layer * 2 + which) * ACTE +
                       (((size_t)(b_ * NH + h)) * TT + t) * DHEAD + d] = f2bf(v);
                }
            }
        }
    }
}

// ---------------- flash attention ----------------
// Grid (B*H, 8)  [bh-major: the 8 p-blocks of a bh share blockIdx mod 8 ->
// same XCD -> K/V panel stays in that XCD's L2 instead of 8x HBM refetch].
// Two q-tiles per block sharing staged KV:
//   causal: (p, 15-p) constant 17 tile-units; cross: (p, p+8).
// Double-buffered KV staging; K/V fragments hoisted to registers ONCE per tile
// and shared by both q-chains; pad/causal mask via ballot bitmask; softmax in
// exp2 domain (Q pre-scaled by QSCALE in the producing GEMM).
// Defer-max (T13): skip alpha/rescale while the wave's max grows <= THR.
template <bool CAUSAL>
__global__ __launch_bounds__(256, 2) void attn_kernel(
    const unsigned short* __restrict__ Q,
    const unsigned short* __restrict__ Kb,
    const unsigned short* __restrict__ Vb,
    const int* __restrict__ tokens,   // [B,1024]; token==0 => masked key
    unsigned short* __restrict__ ctx) // [B,T,512] bf16
{
    __shared__ __attribute__((aligned(16))) short Ks[2][64 * 64];   // [key][d] swizzled
    __shared__ __attribute__((aligned(16))) short Vt[2][64 * 64];   // [d][key] swizzled
    __shared__ __attribute__((aligned(16))) short Pl[2][4][16 * PST];
    __shared__ __attribute__((aligned(16))) float alph[2][4][16];

    const int tid = threadIdx.x, lane = tid & 63, wv = tid >> 6;
    const int quad = lane >> 4, l15 = lane & 15;
    const int p = blockIdx.y;
    const int bh = blockIdx.x;
    const int b = bh >> 3, h = bh & 7;
    const size_t kvbase = (size_t)bh * TT * DHEAD;

    const int qt0 = p;
    const int qt1 = CAUSAL ? (15 - p) : (p + 8);
    const int qg0 = qt0 * 64 + wv * 16 + l15;
    const int qg1 = qt1 * 64 + wv * 16 + l15;

    const bf16x8 qa0 = *(const bf16x8*)&Q[kvbase + (size_t)qg0 * DHEAD + quad * 8];
    const bf16x8 qa1 = *(const bf16x8*)&Q[kvbase + (size_t)qg0 * DHEAD + 32 + quad * 8];
    const bf16x8 qb0 = *(const bf16x8*)&Q[kvbase + (size_t)qg1 * DHEAD + quad * 8];
    const bf16x8 qb1 = *(const bf16x8*)&Q[kvbase + (size_t)qg1 * DHEAD + 32 + quad * 8];

    float4v O0[4], O1[4];
#pragma unroll
    for (int j = 0; j < 4; ++j) { O0[j] = (float4v){0.f,0.f,0.f,0.f}; O1[j] = (float4v){0.f,0.f,0.f,0.f}; }
    float m0_ = -INFINITY, l0_ = 0.f, m1_ = -INFINITY, l1_ = 0.f;

    // staging helpers
    const int key0 = (lane & 31) * 2;            // V-transpose lane roles
    const int d0 = (lane >> 5) * 8 + wv * 16;
    auto stageK = [&](int kt_, int buf) {
#pragma unroll
        for (int i = 0; i < 2; ++i) {
            const int inst = wv * 2 + i;
            const int row = inst * 8 + (lane >> 3);
            const int cb = (lane & 7) ^ (row & 7);
            gl_lds16(Kb + kvbase + (size_t)(kt_ * 64 + row) * DHEAD + cb * 8,
                     (char*)Ks[buf] + inst * 1024);
        }
    };
    auto loadV = [&](int kt_, short8v& r0, short8v& r1) {
        const unsigned short* vp = Vb + kvbase + (size_t)(kt_ * 64 + key0) * DHEAD + d0;
        r0 = *(const short8v*)vp;
        r1 = *(const short8v*)(vp + DHEAD);
    };
    auto writeV = [&](int buf, const short8v& r0, const short8v& r1) {
        const int kc = key0 >> 3, ko = key0 & 7;
#pragma unroll
        for (int j = 0; j < 8; ++j) {
            const int d = d0 + j;
            unsigned pk = (unsigned)(unsigned short)r0[j] |
                          ((unsigned)(unsigned short)r1[j] << 16);
            *(unsigned*)&Vt[buf][d * 64 + ((kc ^ (d & 7)) << 3) + ko] = pk;
        }
    };

    int kt = 0;
    bf16x8 kf[4][2], vf[4][2];  // per-tile fragments, shared by both q-chains

    auto process = [&](int ch, const bf16x8& qf0, const bf16x8& qf1, int qg,
                       float& m, float& l, float4v* O, unsigned long long kbits) {
        // S^T = K * Q^T : D[key][q]   (scores already in exp2 domain)
        float4v st[4];
        __builtin_amdgcn_s_setprio(1);
#pragma unroll
        for (int i = 0; i < 4; ++i) {
            float4v z = (float4v){0.f, 0.f, 0.f, 0.f};
            z = __builtin_amdgcn_mfma_f32_16x16x32_bf16(kf[i][0], qf0, z, 0, 0, 0);
            z = __builtin_amdgcn_mfma_f32_16x16x32_bf16(kf[i][1], qf1, z, 0, 0, 0);
            st[i] = z;
        }
        __builtin_amdgcn_s_setprio(0);
        // combined mask bits: pad keys + (diagonal tile only) causal
        unsigned long long mask = kbits;
        if (CAUSAL && kt * 64 + 63 > qg) {
            const int qcol = qg & 63;
            mask |= (qcol == 63) ? 0ull : (~0ull << (qcol + 1));
        }
        float sv[16], smax = -INFINITY;
#pragma unroll
        for (int i = 0; i < 4; ++i)
#pragma unroll
            for (int r = 0; r < 4; ++r) {
                const int kl = i * 16 + quad * 4 + r;
                float s = ((mask >> kl) & 1ull) ? -1e9f : st[i][r];
                sv[i * 4 + r] = s;
                smax = fmaxf(smax, s);
            }
        smax = fmaxf(smax, __shfl_xor(smax, 16));
        smax = fmaxf(smax, __shfl_xor(smax, 32));
        // defer-max: only rescale when the running max actually grew past THR
        const bool resc = !__all(smax - m <= RESCALE_THR);
        const float mnew = resc ? fmaxf(m, smax) : m;
        float tsum = 0.f;
#pragma unroll
        for (int i = 0; i < 16; ++i) {
            float pv = __builtin_amdgcn_exp2f(sv[i] - mnew);
            sv[i] = pv; tsum += pv;
        }
        tsum += __shfl_xor(tsum, 16);
        tsum += __shfl_xor(tsum, 32);
#pragma unroll
        for (int i = 0; i < 4; ++i) {
            short4v pw;
#pragma unroll
            for (int r = 0; r < 4; ++r) pw[r] = (short)f2bf(sv[i * 4 + r]);
            *(short4v*)&Pl[ch][wv][l15 * PST + i * 16 + quad * 4] = pw;
        }
        if (resc) {
            const float alpha = __builtin_amdgcn_exp2f(m - mnew);
            l = l * alpha + tsum;
            m = mnew;
            if (lane < 16) alph[ch][wv][lane] = alpha;
            const float4v aw = *(const float4v*)&alph[ch][wv][quad * 4];
#pragma unroll
            for (int j = 0; j < 4; ++j) O[j] = O[j] * aw;
        } else {
            l += tsum;
        }
        const bf16x8 p0 = *(const bf16x8*)&Pl[ch][wv][l15 * PST + quad * 8];
        const bf16x8 p1 = *(const bf16x8*)&Pl[ch][wv][l15 * PST + 32 + quad * 8];
        __builtin_amdgcn_s_setprio(1);
#pragma unroll
        for (int j = 0; j < 4; ++j) {
            float4v o = O[j];
            o = __builtin_amdgcn_mfma_f32_16x16x32_bf16(p0, vf[j][0], o, 0, 0, 0);
            o = __builtin_amdgcn_mfma_f32_16x16x32_bf16(p1, vf[j][1], o, 0, 0, 0);
            O[j] = o;
        }
        __builtin_amdgcn_s_setprio(0);
    };

    const int nkt = CAUSAL ? (qt1 + 1) : 16;

    // prologue: stage tile 0 into buffer 0
    stageK(0, 0);
    {
        short8v v0a, v0b;
        loadV(0, v0a, v0b);
        writeV(0, v0a, v0b);
    }
    int tok_cur = tokens[(size_t)b * TT + lane];
    __syncthreads();

    short8v vn0, vn1;
    int tok_next = 0;
    for (kt = 0; kt < nkt; ++kt) {
        const int cur = kt & 1, nxt = cur ^ 1;
        const bool more = (kt + 1 < nkt);
        if (more) {
            stageK(kt + 1, nxt);                       // async DMA into other buffer
            loadV(kt + 1, vn0, vn1);                   // V prefetch into regs
            tok_next = tokens[(size_t)b * TT + (kt + 1) * 64 + lane];
        }
        const unsigned long long kbits = __ballot(tok_cur == 0);

        // hoist K/V fragments once per tile (shared by both chains)
#pragma unroll
        for (int i = 0; i < 4; ++i) {
            const int row = i * 16 + l15;
            const int s0 = quad ^ (row & 7);
            const int s1 = (4 + quad) ^ (row & 7);
            kf[i][0] = *(const bf16x8*)&Ks[cur][row * 64 + s0 * 8];
            kf[i][1] = *(const bf16x8*)&Ks[cur][row * 64 + s1 * 8];
            vf[i][0] = *(const bf16x8*)&Vt[cur][row * 64 + s0 * 8];
            vf[i][1] = *(const bf16x8*)&Vt[cur][row * 64 + s1 * 8];
        }

        if (!CAUSAL || kt <= qt0) process(0, qa0, qa1, qg0, m0_, l0_, O0, kbits);
        process(1, qb0, qb1, qg1, m1_, l1_, O1, kbits);

        if (more) {
            writeV(nxt, vn0, vn1);                     // V regs -> LDS (loads have landed)
            tok_cur = tok_next;
        }
        __syncthreads();                                // drains K DMA (already landed)
    }

    auto finalize = [&](int ch, float l, float4v* O, int qt) {
        if (lane < 16) alph[ch][wv][lane] = l;
        const float4v lw = *(const float4v*)&alph[ch][wv][quad * 4];
        float rl[4];
#pragma unroll
        for (int r = 0; r < 4; ++r) rl[r] = __builtin_amdgcn_rcpf(lw[r]);
#pragma unroll
        for (int j = 0; j < 4; ++j)
#pragma unroll
            for (int r = 0; r < 4; ++r) {
                const int qrow = qt * 64 + wv * 16 + quad * 4 + r;
                ctx[((size_t)b * TT + qrow) * DMODEL + h * DHEAD + j * 16 + l15] =
                    f2bf(O[j][r] * rl[r]);
            }
    };
    finalize(0, l0_, O0, qt0);
    finalize(1, l1_, O1, qt1);
}

// ---------------- host ----------------
extern "C" void kernel_launch(void* const* d_in, const int* in_sizes, int n_in,
                              void* d_out, int out_size, void* d_ws, size_t ws_size,
                              hipStream_t stream)
{
    const int* dec = (const int*)d_in[0];
    const int* enc = (const int*)d_in[1];
    const float* enc_out = (const float*)d_in[2];
    const float* emb = (const float*)d_in[3];
    const float* Wq_s = (const float*)d_in[4];
    const float* Wk_s = (const float*)d_in[5];
    const float* Wv_s = (const float*)d_in[6];
    const float* Wo_s = (const float*)d_in[7];
    const float* Wq_c = (const float*)d_in[8];
    const float* Wk_c = (const float*)d_in[9];
    const float* Wv_c = (const float*)d_in[10];
    const float* Wo_c = (const float*)d_in[11];
    const float* W1 = (const float*)d_in[12];
    const float* W2 = (const float*)d_in[13];
    float* out = (float*)d_out;

    char* p = (char*)d_ws;
    auto carve = [&](size_t bytes) -> char* {
        char* r = p;
        p += (bytes + 255) & ~(size_t)255;
        return r;
    };
    unsigned short* xb   = (unsigned short*)carve(ACTE * 2);
    float* tmp1          = (float*)carve(2 * ACTE * 4);           // 2 split-K partial slices
    unsigned short* qkvb = (unsigned short*)carve(3 * ACTE * 2);  // Q|K|V contiguous
    unsigned short* ctxb = (unsigned short*)carve(ACTE * 2);
    unsigned short* encb = (unsigned short*)carve(ACTE * 2);
    unsigned short* h1   = (unsigned short*)carve((size_t)NTOK * DFF * 2);
    unsigned short* wqkvT = (unsigned short*)carve((size_t)NLAYER * 1536 * 512 * 2);
    unsigned short* woT   = (unsigned short*)carve((size_t)NLAYER * 512 * 512 * 2);
    unsigned short* wqcT  = (unsigned short*)carve((size_t)NLAYER * 512 * 512 * 2);
    unsigned short* wkvcT = (unsigned short*)carve((size_t)NLAYER * 1024 * 512 * 2);
    unsigned short* wocT  = (unsigned short*)carve((size_t)NLAYER * 512 * 512 * 2);
    unsigned short* w1T   = (unsigned short*)carve((size_t)NLAYER * 2048 * 512 * 2);
    unsigned short* w2T   = (unsigned short*)carve((size_t)NLAYER * 512 * 2048 * 2);
    const size_t used = (size_t)(p - (char*)d_ws);
    const bool pre = (used + 12 * ACTE * 2 + 256) <= ws_size;  // all-layer cross K/V cache
    unsigned short* KVc = pre ? (unsigned short*)carve(12 * ACTE * 2) : nullptr;

    // weight prep: 8 small transposes merged into one dispatch
    Tr8Args ta;
    ta.src[0] = Wq_s; ta.dst[0] = wqkvT; ta.dstL[0] = 1536 * 512; ta.rowOff[0] = 0;
    ta.src[1] = Wk_s; ta.dst[1] = wqkvT; ta.dstL[1] = 1536 * 512; ta.rowOff[1] = 512;
    ta.src[2] = Wv_s; ta.dst[2] = wqkvT; ta.dstL[2] = 1536 * 512; ta.rowOff[2] = 1024;
    ta.src[3] = Wo_s; ta.dst[3] = woT;   ta.dstL[3] = 512 * 512;  ta.rowOff[3] = 0;
    ta.src[4] = Wq_c; ta.dst[4] = wqcT;  ta.dstL[4] = 512 * 512;  ta.rowOff[4] = 0;
    ta.src[5] = Wk_c; ta.dst[5] = wkvcT; ta.dstL[5] = 1024 * 512; ta.rowOff[5] = 0;
    ta.src[6] = Wv_c; ta.dst[6] = wkvcT; ta.dstL[6] = 1024 * 512; ta.rowOff[6] = 512;
    ta.src[7] = Wo_c; ta.dst[7] = wocT;  ta.dstL[7] = 512 * 512;  ta.rowOff[7] = 0;
    transpose8_kernel<<<dim3(8, 8, 48), 256, 0, stream>>>(ta);
    transpose_conv_kernel<<<dim3(8, 32, NLAYER), 256, 0, stream>>>(W1, w1T, 512, 2048, (size_t)2048 * 512, 0);
    transpose_conv_kernel<<<dim3(32, 8, NLAYER), 256, 0, stream>>>(W2, w2T, 2048, 512, (size_t)512 * 2048, 0);
    conv_bf16_kernel<<<(int)(ACTE / 1024), 256, 0, stream>>>(enc_out, encb);
    embed_kernel<<<NTOK, 256, 0, stream>>>(dec, emb, xb);

    // cross K/V for ALL layers in one big GEMM (enc side is layer-invariant)
    if (pre)
        gemm_bt<3><<<dim3(64, 48), 256, 0, stream>>>(encb, wkvcT, nullptr, KVc, NTOK, 6144, 512);

    for (int lyr = 0; lyr < NLAYER; ++lyr) {
        const unsigned short* wqkv = wqkvT + (size_t)lyr * 1536 * 512;
        const unsigned short* wo   = woT + (size_t)lyr * 512 * 512;
        const unsigned short* wqc  = wqcT + (size_t)lyr * 512 * 512;
        const unsigned short* wkvc = wkvcT + (size_t)lyr * 1024 * 512;
        const unsigned short* woc  = wocT + (size_t)lyr * 512 * 512;
        const unsigned short* w1   = w1T + (size_t)lyr * 2048 * 512;
        const unsigned short* w2   = w2T + (size_t)lyr * 512 * 2048;

        // ---- self attention ----
        gemm_bt<2><<<dim3(64, 12), 256, 0, stream>>>(xb, wqkv, nullptr, qkvb, NTOK, 1536, 512);
        attn_kernel<true><<<dim3(BB * NH, 8), 256, 0, stream>>>(
            qkvb, qkvb + ACTE, qkvb + 2 * ACTE, dec, ctxb);
        gemm_bt<0, 2><<<dim3(64, 4, 2), 256, 0, stream>>>(ctxb, wo, tmp1, nullptr, NTOK, 512, 512);
        add_ln2<<<NTOK / 4, 256, 0, stream>>>(tmp1, xb, nullptr);

        // ---- cross attention ----
        gemm_bt<2><<<dim3(64, 4), 256, 0, stream>>>(xb, wqc, nullptr, qkvb, NTOK, 512, 512);
        const unsigned short* Kc;
        if (pre) {
            Kc = KVc + (size_t)lyr * 2 * ACTE;
        } else {
            gemm_bt<2><<<dim3(64, 8), 256, 0, stream>>>(encb, wkvc, nullptr, qkvb + ACTE, NTOK, 1024, 512);
            Kc = qkvb + ACTE;
        }
        attn_kernel<false><<<dim3(BB * NH, 8), 256, 0, stream>>>(
            qkvb, Kc, Kc + ACTE, enc, ctxb);
        gemm_bt<0, 2><<<dim3(64, 4, 2), 256, 0, stream>>>(ctxb, woc, tmp1, nullptr, NTOK, 512, 512);
        add_ln2<<<NTOK / 4, 256, 0, stream>>>(tmp1, xb, nullptr);

        // ---- FFN ----
        gemm_bt<1><<<dim3(64, 16), 256, 0, stream>>>(xb, w1, nullptr, h1, NTOK, 2048, 512);
        gemm_bt<0, 2><<<dim3(64, 4, 2), 256, 0, stream>>>(h1, w2, tmp1, nullptr, NTOK, 512, 2048);
        add_ln2<<<NTOK / 4, 256, 0, stream>>>(tmp1, xb, (lyr == NLAYER - 1) ? out : nullptr);
    }
    (void)in_sizes; (void)n_in; (void)out_size;
}

// Round 3
// 1559.685 us; speedup vs baseline: 1.0561x; 1.0324x over previous
//
#include <hip/hip_runtime.h>
#include <hip/hip_bf16.h>

// ---------------- problem constants ----------------
#define DMODEL 512
#define NH     8
#define DHEAD  64
#define DFF    2048
#define NLAYER 6
#define BB     8
#define TT     1024
#define NTOK   (BB*TT)                 // 8192 rows
#define ACTE   ((size_t)NTOK*DMODEL)   // 4,194,304 elements

// Q pre-scale: (1/sqrt(64)) * log2(e)  -> scores arrive in exp2 domain
#define QSCALE 0.18033688011112042f

// defer-max threshold (exp2 domain): skip O-rescale while smax-m <= 8 (P <= 256)
#define RESCALE_THR 8.0f

typedef __bf16  bf16x8  __attribute__((ext_vector_type(8)));
typedef float   float4v __attribute__((ext_vector_type(4)));
typedef short   short4v __attribute__((ext_vector_type(4)));
typedef short   short8v __attribute__((ext_vector_type(8)));

__device__ __forceinline__ unsigned short f2bf(float f) {
    __hip_bfloat16 h = __float2bfloat16(f);
    return *reinterpret_cast<unsigned short*>(&h);
}

// async global->LDS, 16B/lane. LDS base wave-uniform; HW adds lane*16.
// Global address is PER-LANE -> used to write swizzled/permuted LDS layouts free.
__device__ __forceinline__ void gl_lds16(const void* g, void* l) {
    __builtin_amdgcn_global_load_lds((const __attribute__((address_space(1))) void*)g,
                                     (__attribute__((address_space(3))) void*)l, 16, 0, 0);
}

// K-slot permutation (K staging ONLY; V stays identity!):
// slot x = 16i+4q+r holds actual key sigma(x) = 32(i>>1)+8q+4(i&1)+r.
// QK^T lane(q) computes scores at slots {16i+4q+r} = keys {8q+t} u {32+8q+t},
// which is EXACTLY the PV A-fragment key order against identity-staged V
// -> P never leaves registers.
__device__ __forceinline__ int sigma64(int x) {
    return (x & 32) | ((x & 12) << 1) | ((x & 16) >> 2) | (x & 3);
}

// ---------------- merged small-weight transpose (8 types x 6 layers) ----------------
struct Tr8Args {
    const float* src[8];
    unsigned short* dst[8];
    int dstL[8];    // per-layer dst stride (elements)
    int rowOff[8];
};
__global__ __launch_bounds__(256) void transpose8_kernel(Tr8Args a)
{
    __shared__ float tile[64][65];
    const int type = blockIdx.z / 6, lyr = blockIdx.z % 6;
    const float* src = a.src[type] + (size_t)lyr * 512 * 512;
    unsigned short* dst = a.dst[type] + (size_t)lyr * a.dstL[type];
    const int rowOff = a.rowOff[type];
    const int k0 = blockIdx.x * 64, n0 = blockIdx.y * 64;
    const int tid = threadIdx.x;
#pragma unroll
    for (int rep = 0; rep < 16; ++rep) {
        int idx = rep * 256 + tid;
        int r = idx >> 6, c = idx & 63;
        tile[r][c] = src[(size_t)(k0 + r) * 512 + n0 + c];
    }
    __syncthreads();
#pragma unroll
    for (int rep = 0; rep < 16; ++rep) {
        int idx = rep * 256 + tid;
        int r = idx >> 6, c = idx & 63;
        dst[(size_t)(rowOff + n0 + r) * 512 + k0 + c] = f2bf(tile[c][r]);
    }
}

// ---------------- generic transpose (W1/W2) ----------------
__global__ __launch_bounds__(256) void transpose_conv_kernel(
    const float* __restrict__ W, unsigned short* __restrict__ Wt, int K, int N,
    size_t dstL, int rowOff)
{
    __shared__ float tile[64][65];
    const float* src = W + (size_t)blockIdx.z * K * N;
    unsigned short* dst = Wt + (size_t)blockIdx.z * dstL;
    const int k0 = blockIdx.x * 64, n0 = blockIdx.y * 64;
    const int tid = threadIdx.x;
#pragma unroll
    for (int rep = 0; rep < 16; ++rep) {
        int idx = rep * 256 + tid;
        int r = idx >> 6, c = idx & 63;
        tile[r][c] = src[(size_t)(k0 + r) * N + n0 + c];
    }
    __syncthreads();
#pragma unroll
    for (int rep = 0; rep < 16; ++rep) {
        int idx = rep * 256 + tid;
        int r = idx >> 6, c = idx & 63;
        dst[(size_t)(rowOff + n0 + r) * K + k0 + c] = f2bf(tile[c][r]);
    }
}

// ---------------- fp32 -> bf16 convert ----------------
__global__ __launch_bounds__(256) void conv_bf16_kernel(
    const float* __restrict__ in, unsigned short* __restrict__ o)
{
    int i = (blockIdx.x * 256 + threadIdx.x) * 4;
    float4v v = *(const float4v*)(in + i);
    short4v w;
    w[0] = (short)f2bf(v[0]); w[1] = (short)f2bf(v[1]);
    w[2] = (short)f2bf(v[2]); w[3] = (short)f2bf(v[3]);
    *(short4v*)(o + i) = w;
}

// ---------------- embedding + sinusoidal PE (bf16 out only) ----------------
__global__ __launch_bounds__(256) void embed_kernel(
    const int* __restrict__ dec, const float* __restrict__ emb,
    unsigned short* __restrict__ xb)
{
    const int row = blockIdx.x;            // 0..8191
    const int t = row & (TT - 1);
    const int tid = threadIdx.x;
    const int tok = dec[row];
#pragma unroll
    for (int rep = 0; rep < 2; ++rep) {
        int c = tid + rep * 256;
        float e = (tok != 0) ? emb[(size_t)tok * DMODEL + c] : 0.f;
        int j = c >> 1;
        float freq = __expf(-(float)(2 * j) * (9.210340371976184f / 512.f));
        float ang = (float)t * freq;
        float pe = (c & 1) ? cosf(ang) : sinf(ang);
        xb[(size_t)row * DMODEL + c] = f2bf(e + pe);
    }
}

// ---------------- residual add + LayerNorm, wave-per-row ----------------
// y = LN(t[0..ACTE) + t[ACTE..2*ACTE) + bf16(xb));  writes xb (bf16) or xout (fp32).
__global__ __launch_bounds__(256) void add_ln2(
    const float* __restrict__ t, unsigned short* __restrict__ xb,
    float* __restrict__ xout)
{
    const int lane = threadIdx.x & 63;
    const int row = blockIdx.x * 4 + (threadIdx.x >> 6);
    const size_t idx = (size_t)row * DMODEL + lane * 8;
    float4v t0 = *(const float4v*)(t + idx);
    float4v t1 = *(const float4v*)(t + idx + 4);
    float4v u0 = *(const float4v*)(t + ACTE + idx);
    float4v u1 = *(const float4v*)(t + ACTE + idx + 4);
    bf16x8 rb = *(const bf16x8*)(xb + idx);
    float v[8];
#pragma unroll
    for (int k = 0; k < 4; ++k) {
        v[k] = t0[k] + u0[k] + (float)rb[k];
        v[4 + k] = t1[k] + u1[k] + (float)rb[4 + k];
    }
    float s = 0.f, sq = 0.f;
#pragma unroll
    for (int k = 0; k < 8; ++k) { s += v[k]; sq += v[k] * v[k]; }
#pragma unroll
    for (int o = 1; o < 64; o <<= 1) { s += __shfl_xor(s, o); sq += __shfl_xor(sq, o); }
    float mu = s * (1.f / 512.f);
    float var = sq * (1.f / 512.f) - mu * mu;
    float rstd = rsqrtf(var + 1e-5f);
    if (xout) {
        float4v y0, y1;
#pragma unroll
        for (int k = 0; k < 4; ++k) { y0[k] = (v[k] - mu) * rstd; y1[k] = (v[4 + k] - mu) * rstd; }
        *(float4v*)(xout + idx) = y0;
        *(float4v*)(xout + idx + 4) = y1;
    } else {
        short8v w;
#pragma unroll
        for (int k = 0; k < 8; ++k) w[k] = (short)f2bf((v[k] - mu) * rstd);
        *(short8v*)(xb + idx) = w;
    }
}

// ---------------- bf16 GEMM: C[M,N] = A[M,K] * Bt[N,K]^T ----------------
// 128x128 tile, BK=32, 2x2 waves, 4x4 MFMA 16x16x32 per wave.
// LDS XOR-swizzled 16B chunks -> conflict-free ds_read_b128 fragment reads.
// EPI: 0 fp32 (+SPLITK partials); 1 relu->bf16; 2 head-scatter, Q (which==0)
// pre-scaled by QSCALE (exp2-domain softmax); 3 all-layer KV scatter.
template <int EPI, int SPLITK = 1>
__global__ __launch_bounds__(256) void gemm_bt(
    const unsigned short* __restrict__ A,
    const unsigned short* __restrict__ Bt,
    float* __restrict__ Cf,
    unsigned short* __restrict__ Cb,
    int M, int N, int K)
{
    __shared__ __attribute__((aligned(16))) short As[128 * 32];
    __shared__ __attribute__((aligned(16))) short Bs[128 * 32];
    const int tid = threadIdx.x;
    const int lane = tid & 63, wv = tid >> 6;
    const int quad = lane >> 4, l15 = lane & 15;
    const int m0 = blockIdx.x * 128, n0 = blockIdx.y * 128;
    const int wm = wv & 1, wn = wv >> 1;

    float4v acc[4][4];
#pragma unroll
    for (int i = 0; i < 4; ++i)
#pragma unroll
        for (int j = 0; j < 4; ++j) acc[i][j] = (float4v){0.f, 0.f, 0.f, 0.f};

    const int Kc = K / SPLITK;
    const int kbeg = (SPLITK > 1) ? (int)blockIdx.z * Kc : 0;
    for (int k0 = kbeg; k0 < kbeg + Kc; k0 += 32) {
#pragma unroll
        for (int i = 0; i < 2; ++i) {
            const int inst = wv * 2 + i;                  // 0..7, 1KB each
            const int row = inst * 16 + (lane >> 2);      // tile row this lane fills
            const int cb = (lane & 3) ^ ((row >> 1) & 3); // swizzled 16B chunk
            gl_lds16(A + (size_t)(m0 + row) * K + k0 + cb * 8, (char*)As + inst * 1024);
            gl_lds16(Bt + (size_t)(n0 + row) * K + k0 + cb * 8, (char*)Bs + inst * 1024);
        }
        __syncthreads();
        bf16x8 a[4], b[4];
#pragma unroll
        for (int i = 0; i < 4; ++i) {
            const int r = wm * 64 + i * 16 + l15;
            const int st = quad ^ ((r >> 1) & 3);
            a[i] = *(const bf16x8*)&As[r * 32 + st * 8];
        }
#pragma unroll
        for (int j = 0; j < 4; ++j) {
            const int r = wn * 64 + j * 16 + l15;
            const int st = quad ^ ((r >> 1) & 3);
            b[j] = *(const bf16x8*)&Bs[r * 32 + st * 8];
        }
#pragma unroll
        for (int i = 0; i < 4; ++i)
#pragma unroll
            for (int j = 0; j < 4; ++j)
                acc[i][j] = __builtin_amdgcn_mfma_f32_16x16x32_bf16(a[i], b[j], acc[i][j], 0, 0, 0);
        __syncthreads();
    }

    const size_t zoff = (SPLITK > 1) ? (size_t)blockIdx.z * ACTE : 0;
#pragma unroll
    for (int i = 0; i < 4; ++i) {
        const int row_base = m0 + wm * 64 + i * 16 + quad * 4;
#pragma unroll
        for (int j = 0; j < 4; ++j) {
            const int col = n0 + wn * 64 + j * 16 + l15;
#pragma unroll
            for (int r = 0; r < 4; ++r) {
                const int row = row_base + r;
                const float v = acc[i][j][r];
                if (EPI == 0) {
                    Cf[zoff + (size_t)row * N + col] = v;
                } else if (EPI == 1) {
                    Cb[(size_t)row * N + col] = f2bf(fmaxf(v, 0.f));
                } else if (EPI == 2) {
                    const int which = col >> 9;
                    const float sc = (which == 0) ? QSCALE : 1.f;  // pre-scale Q
                    const int b_ = row >> 10, t = row & (TT - 1);
                    const int h = (col >> 6) & 7, d = col & 63;
                    Cb[(size_t)which * ACTE + (((size_t)(b_ * NH + h)) * TT + t) * DHEAD + d] = f2bf(v * sc);
                } else {
                    const int layer = col >> 10, which = (col >> 9) & 1;
                    const int b_ = row >> 10, t = row & (TT - 1);
                    const int h = (col >> 6) & 7, d = col & 63;
                    Cb[(size_t)(layer * 2 + which) * ACTE +
                       (((size_t)(b_ * NH + h)) * TT + t) * DHEAD + d] = f2bf(v);
                }
            }
        }
    }
}

// ---------------- flash attention ----------------
// Grid (B*H, 16): one 64-row q-tile per block, 1024 blocks = 4 blocks/CU.
// bh-major: all q-blocks of a bh land on XCD bh%8 -> K/V stays in that L2.
// Causal: qt = 15 - blockIdx.y (LPT: longest blocks dispatched first).
// K staged sigma-permuted / V staged identity, so the QK^T output fragment
// IS the PV A-fragment: P never touches LDS (no Pl buffer, no conflicts).
// alpha/l cross-quad broadcast via __shfl. Softmax in exp2 domain.
template <bool CAUSAL>
__global__ __launch_bounds__(256, 4) void attn_kernel(
    const unsigned short* __restrict__ Q,
    const unsigned short* __restrict__ Kb,
    const unsigned short* __restrict__ Vb,
    const int* __restrict__ tokens,   // [B,1024]; token==0 => masked key
    unsigned short* __restrict__ ctx) // [B,T,512] bf16
{
    __shared__ __attribute__((aligned(16))) short Ks[2][64 * 64];   // [slot][d] swizzled
    __shared__ __attribute__((aligned(16))) short Vt[2][64 * 64];   // [d][key] swizzled

    const int tid = threadIdx.x, lane = tid & 63, wv = tid >> 6;
    const int quad = lane >> 4, l15 = lane & 15;
    const int bh = blockIdx.x;
    const int qt = CAUSAL ? (15 - (int)blockIdx.y) : (int)blockIdx.y;
    const int b = bh >> 3, h = bh & 7;
    const size_t kvbase = (size_t)bh * TT * DHEAD;

    const int qcol = wv * 16 + l15;        // q index within tile
    const int qg = qt * 64 + qcol;

    const bf16x8 qa0 = *(const bf16x8*)&Q[kvbase + (size_t)qg * DHEAD + quad * 8];
    const bf16x8 qa1 = *(const bf16x8*)&Q[kvbase + (size_t)qg * DHEAD + 32 + quad * 8];

    float4v O[4];
#pragma unroll
    for (int j = 0; j < 4; ++j) O[j] = (float4v){0.f, 0.f, 0.f, 0.f};
    float m_ = -INFINITY, l_ = 0.f;

    const int sig = sigma64(lane);         // K-slot 'lane' holds key sigma(lane)

    // staging helpers (K rows permuted by sigma at the GLOBAL side; V identity)
    const int key0 = (lane & 31) * 2;      // V-transpose lane roles (key index)
    const int d0 = (lane >> 5) * 8 + wv * 16;
    auto stageK = [&](int kt_, int buf) {
#pragma unroll
        for (int i = 0; i < 2; ++i) {
            const int inst = wv * 2 + i;
            const int row = inst * 8 + (lane >> 3);       // slot row
            const int cb = (lane & 7) ^ (row & 7);        // swizzled 16B chunk
            gl_lds16(Kb + kvbase + (size_t)(kt_ * 64 + sigma64(row)) * DHEAD + cb * 8,
                     (char*)Ks[buf] + inst * 1024);
        }
    };
    auto loadV = [&](int kt_, short8v& r0, short8v& r1) {
        const unsigned short* vp = Vb + kvbase + (size_t)(kt_ * 64 + key0) * DHEAD + d0;
        r0 = *(const short8v*)vp;
        r1 = *(const short8v*)(vp + DHEAD);
    };
    auto writeV = [&](int buf, const short8v& r0, const short8v& r1) {
        const int kc = key0 >> 3, ko = key0 & 7;
#pragma unroll
        for (int j = 0; j < 8; ++j) {
            const int d = d0 + j;
            unsigned pk = (unsigned)(unsigned short)r0[j] |
                          ((unsigned)(unsigned short)r1[j] << 16);
            *(unsigned*)&Vt[buf][d * 64 + ((kc ^ (d & 7)) << 3) + ko] = pk;
        }
    };

    const int nkt = CAUSAL ? (qt + 1) : 16;

    // prologue: stage tile 0 into buffer 0
    stageK(0, 0);
    {
        short8v v0a, v0b;
        loadV(0, v0a, v0b);
        writeV(0, v0a, v0b);
    }
    int tok_cur = tokens[(size_t)b * TT + sig];
    __syncthreads();

    short8v vn0, vn1;
    int tok_next = 0;
    for (int kt = 0; kt < nkt; ++kt) {
        const int cur = kt & 1, nxt = cur ^ 1;
        const bool more = (kt + 1 < nkt);
        if (more) {
            stageK(kt + 1, nxt);                       // async DMA into other buffer
            loadV(kt + 1, vn0, vn1);                   // V prefetch into regs
            tok_next = tokens[(size_t)b * TT + (kt + 1) * 64 + sig];
        }
        const unsigned long long kbits = __ballot(tok_cur == 0);

        // ---- S^T = K * Q^T : D[slot][q]  (exp2 domain) ----
        float4v st[4];
        __builtin_amdgcn_s_setprio(1);
#pragma unroll
        for (int i = 0; i < 4; ++i) {
            const int row = i * 16 + l15;
            const int x = row & 7;
            const bf16x8 k0 = *(const bf16x8*)&Ks[cur][row * 64 + ((quad ^ x)) * 8];
            const bf16x8 k1 = *(const bf16x8*)&Ks[cur][row * 64 + (((4 + quad) ^ x)) * 8];
            float4v z = (float4v){0.f, 0.f, 0.f, 0.f};
            z = __builtin_amdgcn_mfma_f32_16x16x32_bf16(k0, qa0, z, 0, 0, 0);
            z = __builtin_amdgcn_mfma_f32_16x16x32_bf16(k1, qa1, z, 0, 0, 0);
            st[i] = z;
        }
        __builtin_amdgcn_s_setprio(0);

        // ---- masking + online softmax (fully in-register) ----
        const bool diag = CAUSAL && (kt == qt);
        const bool domask = (kbits != 0ull) || diag;
        float sv[16], smax = -INFINITY;
        if (domask) {
#pragma unroll
            for (int i = 0; i < 4; ++i)
#pragma unroll
                for (int r = 0; r < 4; ++r) {
                    const int kl = i * 16 + quad * 4 + r;      // slot index
                    const int klocal = sigma64(kl);            // actual key in tile
                    const bool mk = ((kbits >> kl) & 1ull) || (diag && klocal > qcol);
                    const float s = mk ? -1e9f : st[i][r];
                    sv[i * 4 + r] = s;
                    smax = fmaxf(smax, s);
                }
        } else {
#pragma unroll
            for (int i = 0; i < 4; ++i)
#pragma unroll
                for (int r = 0; r < 4; ++r) {
                    const float s = st[i][r];
                    sv[i * 4 + r] = s;
                    smax = fmaxf(smax, s);
                }
        }
        smax = fmaxf(smax, __shfl_xor(smax, 16));
        smax = fmaxf(smax, __shfl_xor(smax, 32));
        // defer-max: only rescale when the running max actually grew past THR
        const bool resc = !__all(smax - m_ <= RESCALE_THR);
        const float mnew = resc ? fmaxf(m_, smax) : m_;
        float tsum = 0.f;
#pragma unroll
        for (int i = 0; i < 16; ++i) {
            float pv = __builtin_amdgcn_exp2f(sv[i] - mnew);
            sv[i] = pv; tsum += pv;
        }
        tsum += __shfl_xor(tsum, 16);
        tsum += __shfl_xor(tsum, 32);

        // P fragments come straight from sv (sigma K-staging made layouts match)
        short8v pw0, pw1;
#pragma unroll
        for (int t = 0; t < 8; ++t) {
            pw0[t] = (short)f2bf(sv[t]);
            pw1[t] = (short)f2bf(sv[8 + t]);
        }
        const bf16x8 p0 = *reinterpret_cast<const bf16x8*>(&pw0);
        const bf16x8 p1 = *reinterpret_cast<const bf16x8*>(&pw1);

        if (resc) {
            const float alpha = __builtin_amdgcn_exp2f(m_ - mnew);
            l_ = l_ * alpha + tsum;
            m_ = mnew;
            // O rows are q = quad*4+r; alpha lives at lane l15=q -> shfl broadcast
            float4v av;
#pragma unroll
            for (int r = 0; r < 4; ++r) av[r] = __shfl(alpha, quad * 4 + r);
#pragma unroll
            for (int j = 0; j < 4; ++j) O[j] = O[j] * av;
        } else {
            l_ += tsum;
        }

        // ---- O += P * V^T ----
        __builtin_amdgcn_s_setprio(1);
#pragma unroll
        for (int j = 0; j < 4; ++j) {
            const int row = j * 16 + l15;
            const int x = row & 7;
            const bf16x8 v0 = *(const bf16x8*)&Vt[cur][row * 64 + ((quad ^ x)) * 8];
            const bf16x8 v1 = *(const bf16x8*)&Vt[cur][row * 64 + (((4 + quad) ^ x)) * 8];
            float4v o = O[j];
            o = __builtin_amdgcn_mfma_f32_16x16x32_bf16(p0, v0, o, 0, 0, 0);
            o = __builtin_amdgcn_mfma_f32_16x16x32_bf16(p1, v1, o, 0, 0, 0);
            O[j] = o;
        }
        __builtin_amdgcn_s_setprio(0);

        if (more) {
            writeV(nxt, vn0, vn1);                     // V regs -> LDS (loads have landed)
            tok_cur = tok_next;
        }
        __syncthreads();                                // drains K DMA (already landed)
    }

    // finalize: divide by l (per q-row; broadcast l15-indexed -> quad*4+r)
    {
        float4v lw;
#pragma unroll
        for (int r = 0; r < 4; ++r) lw[r] = __shfl(l_, quad * 4 + r);
        float rl[4];
#pragma unroll
        for (int r = 0; r < 4; ++r) rl[r] = __builtin_amdgcn_rcpf(lw[r]);
#pragma unroll
        for (int j = 0; j < 4; ++j)
#pragma unroll
            for (int r = 0; r < 4; ++r) {
                const int qrow = qt * 64 + wv * 16 + quad * 4 + r;
                ctx[((size_t)b * TT + qrow) * DMODEL + h * DHEAD + j * 16 + l15] =
                    f2bf(O[j][r] * rl[r]);
            }
    }
}

// ---------------- host ----------------
extern "C" void kernel_launch(void* const* d_in, const int* in_sizes, int n_in,
                              void* d_out, int out_size, void* d_ws, size_t ws_size,
                              hipStream_t stream)
{
    const int* dec = (const int*)d_in[0];
    const int* enc = (const int*)d_in[1];
    const float* enc_out = (const float*)d_in[2];
    const float* emb = (const float*)d_in[3];
    const float* Wq_s = (const float*)d_in[4];
    const float* Wk_s = (const float*)d_in[5];
    const float* Wv_s = (const float*)d_in[6];
    const float* Wo_s = (const float*)d_in[7];
    const float* Wq_c = (const float*)d_in[8];
    const float* Wk_c = (const float*)d_in[9];
    const float* Wv_c = (const float*)d_in[10];
    const float* Wo_c = (const float*)d_in[11];
    const float* W1 = (const float*)d_in[12];
    const float* W2 = (const float*)d_in[13];
    float* out = (float*)d_out;

    char* p = (char*)d_ws;
    auto carve = [&](size_t bytes) -> char* {
        char* r = p;
        p += (bytes + 255) & ~(size_t)255;
        return r;
    };
    unsigned short* xb   = (unsigned short*)carve(ACTE * 2);
    float* tmp1          = (float*)carve(2 * ACTE * 4);           // 2 split-K partial slices
    unsigned short* qkvb = (unsigned short*)carve(3 * ACTE * 2);  // Q|K|V contiguous
    unsigned short* ctxb = (unsigned short*)carve(ACTE * 2);
    unsigned short* encb = (unsigned short*)carve(ACTE * 2);
    unsigned short* h1   = (unsigned short*)carve((size_t)NTOK * DFF * 2);
    unsigned short* wqkvT = (unsigned short*)carve((size_t)NLAYER * 1536 * 512 * 2);
    unsigned short* woT   = (unsigned short*)carve((size_t)NLAYER * 512 * 512 * 2);
    unsigned short* wqcT  = (unsigned short*)carve((size_t)NLAYER * 512 * 512 * 2);
    unsigned short* wkvcT = (unsigned short*)carve((size_t)NLAYER * 1024 * 512 * 2);
    unsigned short* wocT  = (unsigned short*)carve((size_t)NLAYER * 512 * 512 * 2);
    unsigned short* w1T   = (unsigned short*)carve((size_t)NLAYER * 2048 * 512 * 2);
    unsigned short* w2T   = (unsigned short*)carve((size_t)NLAYER * 512 * 2048 * 2);
    const size_t used = (size_t)(p - (char*)d_ws);
    const bool pre = (used + 12 * ACTE * 2 + 256) <= ws_size;  // all-layer cross K/V cache
    unsigned short* KVc = pre ? (unsigned short*)carve(12 * ACTE * 2) : nullptr;

    // weight prep: 8 small transposes merged into one dispatch
    Tr8Args ta;
    ta.src[0] = Wq_s; ta.dst[0] = wqkvT; ta.dstL[0] = 1536 * 512; ta.rowOff[0] = 0;
    ta.src[1] = Wk_s; ta.dst[1] = wqkvT; ta.dstL[1] = 1536 * 512; ta.rowOff[1] = 512;
    ta.src[2] = Wv_s; ta.dst[2] = wqkvT; ta.dstL[2] = 1536 * 512; ta.rowOff[2] = 1024;
    ta.src[3] = Wo_s; ta.dst[3] = woT;   ta.dstL[3] = 512 * 512;  ta.rowOff[3] = 0;
    ta.src[4] = Wq_c; ta.dst[4] = wqcT;  ta.dstL[4] = 512 * 512;  ta.rowOff[4] = 0;
    ta.src[5] = Wk_c; ta.dst[5] = wkvcT; ta.dstL[5] = 1024 * 512; ta.rowOff[5] = 0;
    ta.src[6] = Wv_c; ta.dst[6] = wkvcT; ta.dstL[6] = 1024 * 512; ta.rowOff[6] = 512;
    ta.src[7] = Wo_c; ta.dst[7] = wocT;  ta.dstL[7] = 512 * 512;  ta.rowOff[7] = 0;
    transpose8_kernel<<<dim3(8, 8, 48), 256, 0, stream>>>(ta);
    transpose_conv_kernel<<<dim3(8, 32, NLAYER), 256, 0, stream>>>(W1, w1T, 512, 2048, (size_t)2048 * 512, 0);
    transpose_conv_kernel<<<dim3(32, 8, NLAYER), 256, 0, stream>>>(W2, w2T, 2048, 512, (size_t)512 * 2048, 0);
    conv_bf16_kernel<<<(int)(ACTE / 1024), 256, 0, stream>>>(enc_out, encb);
    embed_kernel<<<NTOK, 256, 0, stream>>>(dec, emb, xb);

    // cross K/V for ALL layers in one big GEMM (enc side is layer-invariant)
    if (pre)
        gemm_bt<3><<<dim3(64, 48), 256, 0, stream>>>(encb, wkvcT, nullptr, KVc, NTOK, 6144, 512);

    for (int lyr = 0; lyr < NLAYER; ++lyr) {
        const unsigned short* wqkv = wqkvT + (size_t)lyr * 1536 * 512;
        const unsigned short* wo   = woT + (size_t)lyr * 512 * 512;
        const unsigned short* wqc  = wqcT + (size_t)lyr * 512 * 512;
        const unsigned short* wkvc = wkvcT + (size_t)lyr * 1024 * 512;
        const unsigned short* woc  = wocT + (size_t)lyr * 512 * 512;
        const unsigned short* w1   = w1T + (size_t)lyr * 2048 * 512;
        const unsigned short* w2   = w2T + (size_t)lyr * 512 * 2048;

        // ---- self attention ----
        gemm_bt<2><<<dim3(64, 12), 256, 0, stream>>>(xb, wqkv, nullptr, qkvb, NTOK, 1536, 512);
        attn_kernel<true><<<dim3(BB * NH, 16), 256, 0, stream>>>(
            qkvb, qkvb + ACTE, qkvb + 2 * ACTE, dec, ctxb);
        gemm_bt<0, 2><<<dim3(64, 4, 2), 256, 0, stream>>>(ctxb, wo, tmp1, nullptr, NTOK, 512, 512);
        add_ln2<<<NTOK / 4, 256, 0, stream>>>(tmp1, xb, nullptr);

        // ---- cross attention ----
        gemm_bt<2><<<dim3(64, 4), 256, 0, stream>>>(xb, wqc, nullptr, qkvb, NTOK, 512, 512);
        const unsigned short* Kc;
        if (pre) {
            Kc = KVc + (size_t)lyr * 2 * ACTE;
        } else {
            gemm_bt<2><<<dim3(64, 8), 256, 0, stream>>>(encb, wkvc, nullptr, qkvb + ACTE, NTOK, 1024, 512);
            Kc = qkvb + ACTE;
        }
        attn_kernel<false><<<dim3(BB * NH, 16), 256, 0, stream>>>(
            qkvb, Kc, Kc + ACTE, enc, ctxb);
        gemm_bt<0, 2><<<dim3(64, 4, 2), 256, 0, stream>>>(ctxb, woc, tmp1, nullptr, NTOK, 512, 512);
        add_ln2<<<NTOK / 4, 256, 0, stream>>>(tmp1, xb, nullptr);

        // ---- FFN ----
        gemm_bt<1><<<dim3(64, 16), 256, 0, stream>>>(xb, w1, nullptr, h1, NTOK, 2048, 512);
        gemm_bt<0, 2><<<dim3(64, 4, 2), 256, 0, stream>>>(h1, w2, tmp1, nullptr, NTOK, 512, 2048);
        add_ln2<<<NTOK / 4, 256, 0, stream>>>(tmp1, xb, (lyr == NLAYER - 1) ? out : nullptr);
    }
    (void)in_sizes; (void)n_in; (void)out_size;
}

// Round 4
// 1474.930 us; speedup vs baseline: 1.1168x; 1.0575x over previous
//
#include <hip/hip_runtime.h>
#include <hip/hip_bf16.h>

// ---------------- problem constants ----------------
#define DMODEL 512
#define NH     8
#define DHEAD  64
#define DFF    2048
#define NLAYER 6
#define BB     8
#define TT     1024
#define NTOK   (BB*TT)                 // 8192 rows
#define ACTE   ((size_t)NTOK*DMODEL)   // 4,194,304 elements

// Q pre-scale: (1/sqrt(64)) * log2(e)  -> scores arrive in exp2 domain
#define QSCALE 0.18033688011112042f

// defer-max threshold (exp2 domain): skip O-rescale while smax-m <= 8 (P <= 256)
#define RESCALE_THR 8.0f

typedef __bf16  bf16x8  __attribute__((ext_vector_type(8)));
typedef float   float4v __attribute__((ext_vector_type(4)));
typedef short   short4v __attribute__((ext_vector_type(4)));
typedef short   short8v __attribute__((ext_vector_type(8)));

__device__ __forceinline__ unsigned short f2bf(float f) {
    __hip_bfloat16 h = __float2bfloat16(f);
    return *reinterpret_cast<unsigned short*>(&h);
}

// async global->LDS, 16B/lane. LDS base wave-uniform; HW adds lane*16.
// Global address is PER-LANE -> used to write swizzled/permuted LDS layouts free.
__device__ __forceinline__ void gl_lds16(const void* g, void* l) {
    __builtin_amdgcn_global_load_lds((const __attribute__((address_space(1))) void*)g,
                                     (__attribute__((address_space(3))) void*)l, 16, 0, 0);
}

// K-slot permutation (K staging ONLY; V stays identity!):
// slot x = 16i+4q+r holds actual key sigma(x) = 32(i>>1)+8q+4(i&1)+r.
// QK^T lane(q) computes scores at slots {16i+4q+r} = keys {8q+t} u {32+8q+t},
// which is EXACTLY the PV A-fragment key order against identity-staged V
// -> P never leaves registers.
__device__ __forceinline__ int sigma64(int x) {
    return (x & 32) | ((x & 12) << 1) | ((x & 16) >> 2) | (x & 3);
}

// ---------------- merged small-weight transpose (8 types x 6 layers) ----------------
struct Tr8Args {
    const float* src[8];
    unsigned short* dst[8];
    int dstL[8];    // per-layer dst stride (elements)
    int rowOff[8];
};
__global__ __launch_bounds__(256) void transpose8_kernel(Tr8Args a)
{
    __shared__ float tile[64][65];
    const int type = blockIdx.z / 6, lyr = blockIdx.z % 6;
    const float* src = a.src[type] + (size_t)lyr * 512 * 512;
    unsigned short* dst = a.dst[type] + (size_t)lyr * a.dstL[type];
    const int rowOff = a.rowOff[type];
    const int k0 = blockIdx.x * 64, n0 = blockIdx.y * 64;
    const int tid = threadIdx.x;
#pragma unroll
    for (int rep = 0; rep < 16; ++rep) {
        int idx = rep * 256 + tid;
        int r = idx >> 6, c = idx & 63;
        tile[r][c] = src[(size_t)(k0 + r) * 512 + n0 + c];
    }
    __syncthreads();
#pragma unroll
    for (int rep = 0; rep < 16; ++rep) {
        int idx = rep * 256 + tid;
        int r = idx >> 6, c = idx & 63;
        dst[(size_t)(rowOff + n0 + r) * 512 + k0 + c] = f2bf(tile[c][r]);
    }
}

// ---------------- generic transpose (W1/W2) ----------------
__global__ __launch_bounds__(256) void transpose_conv_kernel(
    const float* __restrict__ W, unsigned short* __restrict__ Wt, int K, int N,
    size_t dstL, int rowOff)
{
    __shared__ float tile[64][65];
    const float* src = W + (size_t)blockIdx.z * K * N;
    unsigned short* dst = Wt + (size_t)blockIdx.z * dstL;
    const int k0 = blockIdx.x * 64, n0 = blockIdx.y * 64;
    const int tid = threadIdx.x;
#pragma unroll
    for (int rep = 0; rep < 16; ++rep) {
        int idx = rep * 256 + tid;
        int r = idx >> 6, c = idx & 63;
        tile[r][c] = src[(size_t)(k0 + r) * N + n0 + c];
    }
    __syncthreads();
#pragma unroll
    for (int rep = 0; rep < 16; ++rep) {
        int idx = rep * 256 + tid;
        int r = idx >> 6, c = idx & 63;
        dst[(size_t)(rowOff + n0 + r) * K + k0 + c] = f2bf(tile[c][r]);
    }
}

// ---------------- fp32 -> bf16 convert ----------------
__global__ __launch_bounds__(256) void conv_bf16_kernel(
    const float* __restrict__ in, unsigned short* __restrict__ o)
{
    int i = (blockIdx.x * 256 + threadIdx.x) * 4;
    float4v v = *(const float4v*)(in + i);
    short4v w;
    w[0] = (short)f2bf(v[0]); w[1] = (short)f2bf(v[1]);
    w[2] = (short)f2bf(v[2]); w[3] = (short)f2bf(v[3]);
    *(short4v*)(o + i) = w;
}

// ---------------- embedding + sinusoidal PE (bf16 out only) ----------------
__global__ __launch_bounds__(256) void embed_kernel(
    const int* __restrict__ dec, const float* __restrict__ emb,
    unsigned short* __restrict__ xb)
{
    const int row = blockIdx.x;            // 0..8191
    const int t = row & (TT - 1);
    const int tid = threadIdx.x;
    const int tok = dec[row];
#pragma unroll
    for (int rep = 0; rep < 2; ++rep) {
        int c = tid + rep * 256;
        float e = (tok != 0) ? emb[(size_t)tok * DMODEL + c] : 0.f;
        int j = c >> 1;
        float freq = __expf(-(float)(2 * j) * (9.210340371976184f / 512.f));
        float ang = (float)t * freq;
        float pe = (c & 1) ? cosf(ang) : sinf(ang);
        xb[(size_t)row * DMODEL + c] = f2bf(e + pe);
    }
}

// ---------------- residual add + LayerNorm, wave-per-row ----------------
// y = LN(t[0..ACTE) + t[ACTE..2*ACTE) + bf16(xb));  writes xb (bf16) or xout (fp32).
__global__ __launch_bounds__(256) void add_ln2(
    const float* __restrict__ t, unsigned short* __restrict__ xb,
    float* __restrict__ xout)
{
    const int lane = threadIdx.x & 63;
    const int row = blockIdx.x * 4 + (threadIdx.x >> 6);
    const size_t idx = (size_t)row * DMODEL + lane * 8;
    float4v t0 = *(const float4v*)(t + idx);
    float4v t1 = *(const float4v*)(t + idx + 4);
    float4v u0 = *(const float4v*)(t + ACTE + idx);
    float4v u1 = *(const float4v*)(t + ACTE + idx + 4);
    bf16x8 rb = *(const bf16x8*)(xb + idx);
    float v[8];
#pragma unroll
    for (int k = 0; k < 4; ++k) {
        v[k] = t0[k] + u0[k] + (float)rb[k];
        v[4 + k] = t1[k] + u1[k] + (float)rb[4 + k];
    }
    float s = 0.f, sq = 0.f;
#pragma unroll
    for (int k = 0; k < 8; ++k) { s += v[k]; sq += v[k] * v[k]; }
#pragma unroll
    for (int o = 1; o < 64; o <<= 1) { s += __shfl_xor(s, o); sq += __shfl_xor(sq, o); }
    float mu = s * (1.f / 512.f);
    float var = sq * (1.f / 512.f) - mu * mu;
    float rstd = rsqrtf(var + 1e-5f);
    if (xout) {
        float4v y0, y1;
#pragma unroll
        for (int k = 0; k < 4; ++k) { y0[k] = (v[k] - mu) * rstd; y1[k] = (v[4 + k] - mu) * rstd; }
        *(float4v*)(xout + idx) = y0;
        *(float4v*)(xout + idx + 4) = y1;
    } else {
        short8v w;
#pragma unroll
        for (int k = 0; k < 8; ++k) w[k] = (short)f2bf((v[k] - mu) * rstd);
        *(short8v*)(xb + idx) = w;
    }
}

// ---------------- bf16 GEMM: C[M,N] = A[M,K] * Bt[N,K]^T ----------------
// 128x128 tile, BK=64 (2x 32-chunks staged per barrier pair -> 32 MFMAs between
// barriers, half the barrier drains of BK=32), 2x2 waves, 4x4 MFMA 16x16x32/wave.
// LDS XOR-swizzled 16B chunks -> conflict-free ds_read_b128 fragment reads.
// EPI: 0 fp32 (+SPLITK partials); 1 relu->bf16; 2 head-scatter, Q (which==0)
// pre-scaled by QSCALE (exp2-domain softmax); 3 all-layer KV scatter.
template <int EPI, int SPLITK = 1>
__global__ __launch_bounds__(256) void gemm_bt(
    const unsigned short* __restrict__ A,
    const unsigned short* __restrict__ Bt,
    float* __restrict__ Cf,
    unsigned short* __restrict__ Cb,
    int M, int N, int K)
{
    __shared__ __attribute__((aligned(16))) short As[2 * 128 * 32];
    __shared__ __attribute__((aligned(16))) short Bs[2 * 128 * 32];
    const int tid = threadIdx.x;
    const int lane = tid & 63, wv = tid >> 6;
    const int quad = lane >> 4, l15 = lane & 15;
    const int m0 = blockIdx.x * 128, n0 = blockIdx.y * 128;
    const int wm = wv & 1, wn = wv >> 1;

    float4v acc[4][4];
#pragma unroll
    for (int i = 0; i < 4; ++i)
#pragma unroll
        for (int j = 0; j < 4; ++j) acc[i][j] = (float4v){0.f, 0.f, 0.f, 0.f};

    const int Kc = K / SPLITK;          // multiple of 64 at every call site
    const int kbeg = (SPLITK > 1) ? (int)blockIdx.z * Kc : 0;
    for (int k0 = kbeg; k0 < kbeg + Kc; k0 += 64) {
#pragma unroll
        for (int c = 0; c < 2; ++c)
#pragma unroll
            for (int i = 0; i < 2; ++i) {
                const int inst = wv * 2 + i;                  // 0..7, 1KB each
                const int row = inst * 16 + (lane >> 2);      // tile row this lane fills
                const int cb = (lane & 3) ^ ((row >> 1) & 3); // swizzled 16B chunk
                gl_lds16(A + (size_t)(m0 + row) * K + k0 + c * 32 + cb * 8,
                         (char*)As + c * 8192 + inst * 1024);
                gl_lds16(Bt + (size_t)(n0 + row) * K + k0 + c * 32 + cb * 8,
                         (char*)Bs + c * 8192 + inst * 1024);
            }
        __syncthreads();
#pragma unroll
        for (int c = 0; c < 2; ++c) {
            bf16x8 a[4], b[4];
#pragma unroll
            for (int i = 0; i < 4; ++i) {
                const int r = wm * 64 + i * 16 + l15;
                const int st = quad ^ ((r >> 1) & 3);
                a[i] = *(const bf16x8*)&As[c * 4096 + r * 32 + st * 8];
            }
#pragma unroll
            for (int j = 0; j < 4; ++j) {
                const int r = wn * 64 + j * 16 + l15;
                const int st = quad ^ ((r >> 1) & 3);
                b[j] = *(const bf16x8*)&Bs[c * 4096 + r * 32 + st * 8];
            }
#pragma unroll
            for (int i = 0; i < 4; ++i)
#pragma unroll
                for (int j = 0; j < 4; ++j)
                    acc[i][j] = __builtin_amdgcn_mfma_f32_16x16x32_bf16(a[i], b[j], acc[i][j], 0, 0, 0);
        }
        __syncthreads();
    }

    const size_t zoff = (SPLITK > 1) ? (size_t)blockIdx.z * ACTE : 0;
#pragma unroll
    for (int i = 0; i < 4; ++i) {
        const int row_base = m0 + wm * 64 + i * 16 + quad * 4;
#pragma unroll
        for (int j = 0; j < 4; ++j) {
            const int col = n0 + wn * 64 + j * 16 + l15;
#pragma unroll
            for (int r = 0; r < 4; ++r) {
                const int row = row_base + r;
                const float v = acc[i][j][r];
                if (EPI == 0) {
                    Cf[zoff + (size_t)row * N + col] = v;
                } else if (EPI == 1) {
                    Cb[(size_t)row * N + col] = f2bf(fmaxf(v, 0.f));
                } else if (EPI == 2) {
                    const int which = col >> 9;
                    const float sc = (which == 0) ? QSCALE : 1.f;  // pre-scale Q
                    const int b_ = row >> 10, t = row & (TT - 1);
                    const int h = (col >> 6) & 7, d = col & 63;
                    Cb[(size_t)which * ACTE + (((size_t)(b_ * NH + h)) * TT + t) * DHEAD + d] = f2bf(v * sc);
                } else {
                    const int layer = col >> 10, which = (col >> 9) & 1;
                    const int b_ = row >> 10, t = row & (TT - 1);
                    const int h = (col >> 6) & 7, d = col & 63;
                    Cb[(size_t)(layer * 2 + which) * ACTE +
                       (((size_t)(b_ * NH + h)) * TT + t) * DHEAD + d] = f2bf(v);
                }
            }
        }
    }
}

// ---------------- flash attention ----------------
// CHAINS=1 (causal): grid (64,16), one q-tile/block, 4 blocks/CU (Round-2 form).
// CHAINS=2 (cross):  grid (64,8), q-tiles (p, p+8) share each staged K/V tile:
//   K/V frags hoisted to registers once per tile -> staging, barriers and
//   V-transpose VALU amortized over 2 chains (halves total tile-visits).
// bh-major grid: all q-blocks of a bh land on XCD bh%8 -> K/V stays in its L2.
// K staged sigma-permuted / V identity, so the QK^T output fragment IS the PV
// A-fragment: P never touches LDS. Softmax in exp2 domain; defer-max rescale.
template <bool CAUSAL, int CHAINS>
__global__ __launch_bounds__(256, (CHAINS == 1 ? 4 : 2)) void attn_kernel(
    const unsigned short* __restrict__ Q,
    const unsigned short* __restrict__ Kb,
    const unsigned short* __restrict__ Vb,
    const int* __restrict__ tokens,   // [B,1024]; token==0 => masked key
    unsigned short* __restrict__ ctx) // [B,T,512] bf16
{
    __shared__ __attribute__((aligned(16))) short Ks[2][64 * 64];   // [slot][d] swizzled
    __shared__ __attribute__((aligned(16))) short Vt[2][64 * 64];   // [d][key] swizzled

    const int tid = threadIdx.x, lane = tid & 63, wv = tid >> 6;
    const int quad = lane >> 4, l15 = lane & 15;
    const int bh = blockIdx.x;
    const int qt0 = CAUSAL ? (15 - (int)blockIdx.y) : (int)blockIdx.y;
    const int qt1 = qt0 + 8;                      // used only when CHAINS==2
    const int b = bh >> 3, h = bh & 7;
    const size_t kvbase = (size_t)bh * TT * DHEAD;

    const int qcol = wv * 16 + l15;               // q index within tile
    const int qg0 = qt0 * 64 + qcol;
    const int qg1 = qt1 * 64 + qcol;

    const bf16x8 qa0 = *(const bf16x8*)&Q[kvbase + (size_t)qg0 * DHEAD + quad * 8];
    const bf16x8 qa1 = *(const bf16x8*)&Q[kvbase + (size_t)qg0 * DHEAD + 32 + quad * 8];
    bf16x8 qb0, qb1;
    if (CHAINS == 2) {
        qb0 = *(const bf16x8*)&Q[kvbase + (size_t)qg1 * DHEAD + quad * 8];
        qb1 = *(const bf16x8*)&Q[kvbase + (size_t)qg1 * DHEAD + 32 + quad * 8];
    }

    float4v O0[4], O1[4];
#pragma unroll
    for (int j = 0; j < 4; ++j) { O0[j] = (float4v){0.f,0.f,0.f,0.f}; O1[j] = (float4v){0.f,0.f,0.f,0.f}; }
    float m0_ = -INFINITY, l0_ = 0.f, m1_ = -INFINITY, l1_ = 0.f;

    const int sig = sigma64(lane);         // K-slot 'lane' holds key sigma(lane)

    // staging helpers (K rows permuted by sigma at the GLOBAL side; V identity)
    const int key0 = (lane & 31) * 2;      // V-transpose lane roles (key index)
    const int d0 = (lane >> 5) * 8 + wv * 16;
    auto stageK = [&](int kt_, int buf) {
#pragma unroll
        for (int i = 0; i < 2; ++i) {
            const int inst = wv * 2 + i;
            const int row = inst * 8 + (lane >> 3);       // slot row
            const int cb = (lane & 7) ^ (row & 7);        // swizzled 16B chunk
            gl_lds16(Kb + kvbase + (size_t)(kt_ * 64 + sigma64(row)) * DHEAD + cb * 8,
                     (char*)Ks[buf] + inst * 1024);
        }
    };
    auto loadV = [&](int kt_, short8v& r0, short8v& r1) {
        const unsigned short* vp = Vb + kvbase + (size_t)(kt_ * 64 + key0) * DHEAD + d0;
        r0 = *(const short8v*)vp;
        r1 = *(const short8v*)(vp + DHEAD);
    };
    auto writeV = [&](int buf, const short8v& r0, const short8v& r1) {
        const int kc = key0 >> 3, ko = key0 & 7;
#pragma unroll
        for (int j = 0; j < 8; ++j) {
            const int d = d0 + j;
            unsigned pk = (unsigned)(unsigned short)r0[j] |
                          ((unsigned)(unsigned short)r1[j] << 16);
            *(unsigned*)&Vt[buf][d * 64 + ((kc ^ (d & 7)) << 3) + ko] = pk;
        }
    };

    // in-register online softmax: st -> (p0,p1), updates m/l and rescales O
    auto softmax_step = [&](const float4v* st, unsigned long long kbits, bool diag,
                            float& m, float& l, float4v* O, bf16x8& p0, bf16x8& p1) {
        const bool domask = (kbits != 0ull) || diag;
        float sv[16], smax = -INFINITY;
        if (domask) {
#pragma unroll
            for (int i = 0; i < 4; ++i)
#pragma unroll
                for (int r = 0; r < 4; ++r) {
                    const int kl = i * 16 + quad * 4 + r;      // slot index
                    const int klocal = sigma64(kl);            // actual key in tile
                    const bool mk = ((kbits >> kl) & 1ull) || (diag && klocal > qcol);
                    const float s = mk ? -1e9f : st[i][r];
                    sv[i * 4 + r] = s;
                    smax = fmaxf(smax, s);
                }
        } else {
#pragma unroll
            for (int i = 0; i < 4; ++i)
#pragma unroll
                for (int r = 0; r < 4; ++r) {
                    const float s = st[i][r];
                    sv[i * 4 + r] = s;
                    smax = fmaxf(smax, s);
                }
        }
        smax = fmaxf(smax, __shfl_xor(smax, 16));
        smax = fmaxf(smax, __shfl_xor(smax, 32));
        const bool resc = !__all(smax - m <= RESCALE_THR);
        const float mnew = resc ? fmaxf(m, smax) : m;
        float tsum = 0.f;
#pragma unroll
        for (int i = 0; i < 16; ++i) {
            float pv = __builtin_amdgcn_exp2f(sv[i] - mnew);
            sv[i] = pv; tsum += pv;
        }
        tsum += __shfl_xor(tsum, 16);
        tsum += __shfl_xor(tsum, 32);
        short8v pw0, pw1;
#pragma unroll
        for (int t = 0; t < 8; ++t) {
            pw0[t] = (short)f2bf(sv[t]);
            pw1[t] = (short)f2bf(sv[8 + t]);
        }
        p0 = *reinterpret_cast<const bf16x8*>(&pw0);
        p1 = *reinterpret_cast<const bf16x8*>(&pw1);
        if (resc) {
            const float alpha = __builtin_amdgcn_exp2f(m - mnew);
            l = l * alpha + tsum;
            m = mnew;
            float4v av;
#pragma unroll
            for (int r = 0; r < 4; ++r) av[r] = __shfl(alpha, quad * 4 + r);
#pragma unroll
            for (int j = 0; j < 4; ++j) O[j] = O[j] * av;
        } else {
            l += tsum;
        }
    };

    const int nkt = CAUSAL ? (qt0 + 1) : 16;

    // prologue: stage tile 0 into buffer 0
    stageK(0, 0);
    {
        short8v v0a, v0b;
        loadV(0, v0a, v0b);
        writeV(0, v0a, v0b);
    }
    int tok_cur = tokens[(size_t)b * TT + sig];
    __syncthreads();

    short8v vn0, vn1;
    int tok_next = 0;
    for (int kt = 0; kt < nkt; ++kt) {
        const int cur = kt & 1, nxt = cur ^ 1;
        const bool more = (kt + 1 < nkt);
        if (more) {
            stageK(kt + 1, nxt);                       // async DMA into other buffer
            loadV(kt + 1, vn0, vn1);                   // V prefetch into regs
            tok_next = tokens[(size_t)b * TT + (kt + 1) * 64 + sig];
        }
        const unsigned long long kbits = __ballot(tok_cur == 0);

        if (CHAINS == 1) {
            // ---- single chain: frag reads folded into MFMA loops (low VGPR) ----
            float4v st[4];
            __builtin_amdgcn_s_setprio(1);
#pragma unroll
            for (int i = 0; i < 4; ++i) {
                const int row = i * 16 + l15;
                const int x = row & 7;
                const bf16x8 k0 = *(const bf16x8*)&Ks[cur][row * 64 + ((quad ^ x)) * 8];
                const bf16x8 k1 = *(const bf16x8*)&Ks[cur][row * 64 + (((4 + quad) ^ x)) * 8];
                float4v z = (float4v){0.f, 0.f, 0.f, 0.f};
                z = __builtin_amdgcn_mfma_f32_16x16x32_bf16(k0, qa0, z, 0, 0, 0);
                z = __builtin_amdgcn_mfma_f32_16x16x32_bf16(k1, qa1, z, 0, 0, 0);
                st[i] = z;
            }
            __builtin_amdgcn_s_setprio(0);
            bf16x8 p0, p1;
            softmax_step(st, kbits, CAUSAL && (kt == qt0), m0_, l0_, O0, p0, p1);
            __builtin_amdgcn_s_setprio(1);
#pragma unroll
            for (int j = 0; j < 4; ++j) {
                const int row = j * 16 + l15;
                const int x = row & 7;
                const bf16x8 v0 = *(const bf16x8*)&Vt[cur][row * 64 + ((quad ^ x)) * 8];
                const bf16x8 v1 = *(const bf16x8*)&Vt[cur][row * 64 + (((4 + quad) ^ x)) * 8];
                float4v o = O0[j];
                o = __builtin_amdgcn_mfma_f32_16x16x32_bf16(p0, v0, o, 0, 0, 0);
                o = __builtin_amdgcn_mfma_f32_16x16x32_bf16(p1, v1, o, 0, 0, 0);
                O0[j] = o;
            }
            __builtin_amdgcn_s_setprio(0);
        } else {
            // ---- two chains: hoist K/V frags once, share across both chains ----
            bf16x8 kf[4][2], vf[4][2];
#pragma unroll
            for (int i = 0; i < 4; ++i) {
                const int row = i * 16 + l15;
                const int x = row & 7;
                kf[i][0] = *(const bf16x8*)&Ks[cur][row * 64 + ((quad ^ x)) * 8];
                kf[i][1] = *(const bf16x8*)&Ks[cur][row * 64 + (((4 + quad) ^ x)) * 8];
                vf[i][0] = *(const bf16x8*)&Vt[cur][row * 64 + ((quad ^ x)) * 8];
                vf[i][1] = *(const bf16x8*)&Vt[cur][row * 64 + (((4 + quad) ^ x)) * 8];
            }
#pragma unroll
            for (int ch = 0; ch < 2; ++ch) {
                const bf16x8& qf0 = ch ? qb0 : qa0;
                const bf16x8& qf1 = ch ? qb1 : qa1;
                float& m = ch ? m1_ : m0_;
                float& l = ch ? l1_ : l0_;
                float4v* O = ch ? O1 : O0;
                float4v st[4];
                __builtin_amdgcn_s_setprio(1);
#pragma unroll
                for (int i = 0; i < 4; ++i) {
                    float4v z = (float4v){0.f, 0.f, 0.f, 0.f};
                    z = __builtin_amdgcn_mfma_f32_16x16x32_bf16(kf[i][0], qf0, z, 0, 0, 0);
                    z = __builtin_amdgcn_mfma_f32_16x16x32_bf16(kf[i][1], qf1, z, 0, 0, 0);
                    st[i] = z;
                }
                __builtin_amdgcn_s_setprio(0);
                bf16x8 p0, p1;
                softmax_step(st, kbits, false, m, l, O, p0, p1);
                __builtin_amdgcn_s_setprio(1);
#pragma unroll
                for (int j = 0; j < 4; ++j) {
                    float4v o = O[j];
                    o = __builtin_amdgcn_mfma_f32_16x16x32_bf16(p0, vf[j][0], o, 0, 0, 0);
                    o = __builtin_amdgcn_mfma_f32_16x16x32_bf16(p1, vf[j][1], o, 0, 0, 0);
                    O[j] = o;
                }
                __builtin_amdgcn_s_setprio(0);
            }
        }

        if (more) {
            writeV(nxt, vn0, vn1);                     // V regs -> LDS (loads have landed)
            tok_cur = tok_next;
        }
        __syncthreads();                                // drains K DMA (already landed)
    }

    // finalize: divide by l (per q-row; broadcast l15-indexed -> quad*4+r)
    auto finalize = [&](float l, float4v* O, int qt) {
        float4v lw;
#pragma unroll
        for (int r = 0; r < 4; ++r) lw[r] = __shfl(l, quad * 4 + r);
        float rl[4];
#pragma unroll
        for (int r = 0; r < 4; ++r) rl[r] = __builtin_amdgcn_rcpf(lw[r]);
#pragma unroll
        for (int j = 0; j < 4; ++j)
#pragma unroll
            for (int r = 0; r < 4; ++r) {
                const int qrow = qt * 64 + wv * 16 + quad * 4 + r;
                ctx[((size_t)b * TT + qrow) * DMODEL + h * DHEAD + j * 16 + l15] =
                    f2bf(O[j][r] * rl[r]);
            }
    };
    finalize(l0_, O0, qt0);
    if (CHAINS == 2) finalize(l1_, O1, qt1);
}

// ---------------- host ----------------
extern "C" void kernel_launch(void* const* d_in, const int* in_sizes, int n_in,
                              void* d_out, int out_size, void* d_ws, size_t ws_size,
                              hipStream_t stream)
{
    const int* dec = (const int*)d_in[0];
    const int* enc = (const int*)d_in[1];
    const float* enc_out = (const float*)d_in[2];
    const float* emb = (const float*)d_in[3];
    const float* Wq_s = (const float*)d_in[4];
    const float* Wk_s = (const float*)d_in[5];
    const float* Wv_s = (const float*)d_in[6];
    const float* Wo_s = (const float*)d_in[7];
    const float* Wq_c = (const float*)d_in[8];
    const float* Wk_c = (const float*)d_in[9];
    const float* Wv_c = (const float*)d_in[10];
    const float* Wo_c = (const float*)d_in[11];
    const float* W1 = (const float*)d_in[12];
    const float* W2 = (const float*)d_in[13];
    float* out = (float*)d_out;

    char* p = (char*)d_ws;
    auto carve = [&](size_t bytes) -> char* {
        char* r = p;
        p += (bytes + 255) & ~(size_t)255;
        return r;
    };
    unsigned short* xb   = (unsigned short*)carve(ACTE * 2);
    float* tmp1          = (float*)carve(2 * ACTE * 4);           // 2 split-K partial slices
    unsigned short* qkvb = (unsigned short*)carve(3 * ACTE * 2);  // Q|K|V contiguous
    unsigned short* ctxb = (unsigned short*)carve(ACTE * 2);
    unsigned short* encb = (unsigned short*)carve(ACTE * 2);
    unsigned short* h1   = (unsigned short*)carve((size_t)NTOK * DFF * 2);
    unsigned short* wqkvT = (unsigned short*)carve((size_t)NLAYER * 1536 * 512 * 2);
    unsigned short* woT   = (unsigned short*)carve((size_t)NLAYER * 512 * 512 * 2);
    unsigned short* wqcT  = (unsigned short*)carve((size_t)NLAYER * 512 * 512 * 2);
    unsigned short* wkvcT = (unsigned short*)carve((size_t)NLAYER * 1024 * 512 * 2);
    unsigned short* wocT  = (unsigned short*)carve((size_t)NLAYER * 512 * 512 * 2);
    unsigned short* w1T   = (unsigned short*)carve((size_t)NLAYER * 2048 * 512 * 2);
    unsigned short* w2T   = (unsigned short*)carve((size_t)NLAYER * 512 * 2048 * 2);
    const size_t used = (size_t)(p - (char*)d_ws);
    const bool pre = (used + 12 * ACTE * 2 + 256) <= ws_size;  // all-layer cross K/V cache
    unsigned short* KVc = pre ? (unsigned short*)carve(12 * ACTE * 2) : nullptr;

    // weight prep: 8 small transposes merged into one dispatch
    Tr8Args ta;
    ta.src[0] = Wq_s; ta.dst[0] = wqkvT; ta.dstL[0] = 1536 * 512; ta.rowOff[0] = 0;
    ta.src[1] = Wk_s; ta.dst[1] = wqkvT; ta.dstL[1] = 1536 * 512; ta.rowOff[1] = 512;
    ta.src[2] = Wv_s; ta.dst[2] = wqkvT; ta.dstL[2] = 1536 * 512; ta.rowOff[2] = 1024;
    ta.src[3] = Wo_s; ta.dst[3] = woT;   ta.dstL[3] = 512 * 512;  ta.rowOff[3] = 0;
    ta.src[4] = Wq_c; ta.dst[4] = wqcT;  ta.dstL[4] = 512 * 512;  ta.rowOff[4] = 0;
    ta.src[5] = Wk_c; ta.dst[5] = wkvcT; ta.dstL[5] = 1024 * 512; ta.rowOff[5] = 0;
    ta.src[6] = Wv_c; ta.dst[6] = wkvcT; ta.dstL[6] = 1024 * 512; ta.rowOff[6] = 512;
    ta.src[7] = Wo_c; ta.dst[7] = wocT;  ta.dstL[7] = 512 * 512;  ta.rowOff[7] = 0;
    transpose8_kernel<<<dim3(8, 8, 48), 256, 0, stream>>>(ta);
    transpose_conv_kernel<<<dim3(8, 32, NLAYER), 256, 0, stream>>>(W1, w1T, 512, 2048, (size_t)2048 * 512, 0);
    transpose_conv_kernel<<<dim3(32, 8, NLAYER), 256, 0, stream>>>(W2, w2T, 2048, 512, (size_t)512 * 2048, 0);
    conv_bf16_kernel<<<(int)(ACTE / 1024), 256, 0, stream>>>(enc_out, encb);
    embed_kernel<<<NTOK, 256, 0, stream>>>(dec, emb, xb);

    // cross K/V for ALL layers in one big GEMM (enc side is layer-invariant)
    if (pre)
        gemm_bt<3><<<dim3(64, 48), 256, 0, stream>>>(encb, wkvcT, nullptr, KVc, NTOK, 6144, 512);

    for (int lyr = 0; lyr < NLAYER; ++lyr) {
        const unsigned short* wqkv = wqkvT + (size_t)lyr * 1536 * 512;
        const unsigned short* wo   = woT + (size_t)lyr * 512 * 512;
        const unsigned short* wqc  = wqcT + (size_t)lyr * 512 * 512;
        const unsigned short* wkvc = wkvcT + (size_t)lyr * 1024 * 512;
        const unsigned short* woc  = wocT + (size_t)lyr * 512 * 512;
        const unsigned short* w1   = w1T + (size_t)lyr * 2048 * 512;
        const unsigned short* w2   = w2T + (size_t)lyr * 512 * 2048;

        // ---- self attention ----
        gemm_bt<2><<<dim3(64, 12), 256, 0, stream>>>(xb, wqkv, nullptr, qkvb, NTOK, 1536, 512);
        attn_kernel<true, 1><<<dim3(BB * NH, 16), 256, 0, stream>>>(
            qkvb, qkvb + ACTE, qkvb + 2 * ACTE, dec, ctxb);
        gemm_bt<0, 2><<<dim3(64, 4, 2), 256, 0, stream>>>(ctxb, wo, tmp1, nullptr, NTOK, 512, 512);
        add_ln2<<<NTOK / 4, 256, 0, stream>>>(tmp1, xb, nullptr);

        // ---- cross attention ----
        gemm_bt<2><<<dim3(64, 4), 256, 0, stream>>>(xb, wqc, nullptr, qkvb, NTOK, 512, 512);
        const unsigned short* Kc;
        if (pre) {
            Kc = KVc + (size_t)lyr * 2 * ACTE;
        } else {
            gemm_bt<2><<<dim3(64, 8), 256, 0, stream>>>(encb, wkvc, nullptr, qkvb + ACTE, NTOK, 1024, 512);
            Kc = qkvb + ACTE;
        }
        attn_kernel<false, 2><<<dim3(BB * NH, 8), 256, 0, stream>>>(
            qkvb, Kc, Kc + ACTE, enc, ctxb);
        gemm_bt<0, 2><<<dim3(64, 4, 2), 256, 0, stream>>>(ctxb, woc, tmp1, nullptr, NTOK, 512, 512);
        add_ln2<<<NTOK / 4, 256, 0, stream>>>(tmp1, xb, nullptr);

        // ---- FFN ----
        gemm_bt<1><<<dim3(64, 16), 256, 0, stream>>>(xb, w1, nullptr, h1, NTOK, 2048, 512);
        gemm_bt<0, 2><<<dim3(64, 4, 2), 256, 0, stream>>>(h1, w2, tmp1, nullptr, NTOK, 512, 2048);
        add_ln2<<<NTOK / 4, 256, 0, stream>>>(tmp1, xb, (lyr == NLAYER - 1) ? out : nullptr);
    }
    (void)in_sizes; (void)n_in; (void)out_size;
}